// Round 11
// baseline (62.519 us; speedup 1.0000x reference)
//
#include <hip/hip_runtime.h>
#include <math.h>

// Problem constants
#define BATCH 32
#define SEQ   512
#define DIN   512
#define IFACE 919
#define TAILC 274     // iface columns 645..918 are the only ones used
#define TAIL0 645

// ws float offsets
#define XM_PART 0        // 32*64*512 = 1048576 (partial seq sums, 64 chunks/batch)
#define EVO     1048576  // 32*128 sigmoid(erase)
#define WVO     1052672  // 32*128 write vector
#define WWH     1056768  // 32*64  ww for n<64
#define SCAL    1058816  // 32*2   [u, wwc]
#define RWV     1058880  // 32*4   rw per head

// d_out float offsets (tuple concat: out, memory, link, usage, prec, ww, rw)
#define OUT_OFF   0
#define MEM_OFF   16384
#define LINK_OFF  4210688      // 32*1024*1024 floats of exact zeros
#define USAGE_OFF 37765120
#define PREC_OFF  37797888
#define WW_OFF    37830656
#define RW_OFF    37863424

// kW unit space (float4 units). Total = 9469952 = 9248 blocks * 1024 exactly.
#define L_END 8388608                  // link zeros
#define M_END (L_END + 1048576)        // memory fill
#define U_END (M_END + 8192)           // usage
#define P_END (U_END + 8192)           // prec
#define WW_END (P_END + 8192)          // ww
#define R_END (WW_END + 32768)         // rw
#define KW_BLOCKS 9248

__device__ __forceinline__ float sigmoidf_(float x) { return 1.0f / (1.0f + expf(-x)); }

// K1: partial reduce of x over seq. grid (64 chunks, 32 batch), 128 threads.
// Chunk = 8 consecutive seq rows; 8 float4 loads/thread; 16 waves/CU occupancy.
__global__ void k_reduce_x(const float* __restrict__ x, float* __restrict__ ws) {
    int c = blockIdx.x, b = blockIdx.y, t = threadIdx.x;
    const float4* xr = (const float4*)(x + (size_t)(b * SEQ + c * 8) * DIN);
    float4 acc = {0.f, 0.f, 0.f, 0.f};
    #pragma unroll
    for (int s = 0; s < 8; ++s) {
        float4 v = xr[s * 128 + t];
        acc.x += v.x; acc.y += v.y; acc.z += v.z; acc.w += v.w;
    }
    ((float4*)(ws + XM_PART))[(b * 64 + c) * 128 + t] = acc;
}

// K2: one block per batch, 512 threads. Finish reduce -> GEMV (1 col/thread) -> params.
__global__ __launch_bounds__(512) void kB(float* __restrict__ ws,
                                          const float* __restrict__ Wif,
                                          float* __restrict__ out) {
    __shared__ float xms[DIN];
    __shared__ float p[TAILC];
    int b = blockIdx.x, t = threadIdx.x;

    {   // finish the two-stage reduce: sum 64 partials for dim t (coalesced per c)
        const float* q = ws + XM_PART + (size_t)b * 64 * DIN + t;
        float s = 0.f;
        #pragma unroll 8
        for (int c = 0; c < 64; ++c) s += q[c * DIN];
        xms[t] = s;
    }
    __syncthreads();

    if (t < TAILC) {   // GEMV: one column per thread (coalesced over t per k)
        const float* wcol = Wif + TAIL0 + t;
        float acc = 0.f;
        #pragma unroll 8
        for (int k = 0; k < DIN; ++k) acc += xms[k] * wcol[(size_t)k * IFACE];
        p[t] = acc * (1.0f / SEQ);
    }
    __syncthreads();

    // read_modes softmax, middle mode (redundant per thread, reads shared p)
    float rm1[4];
    #pragma unroll
    for (int r = 0; r < 4; ++r) {
        float i0 = p[262 + r], i1 = p[266 + r], i2 = p[270 + r];
        float mx = fmaxf(i0, fmaxf(i1, i2));
        float e0 = expf(i0 - mx), e1 = expf(i1 - mx), e2 = expf(i2 - mx);
        rm1[r] = e1 / (e0 + e1 + e2);
    }

    if (t < 128) {
        ws[EVO + b * 128 + t] = sigmoidf_(p[t]);          // sigmoid(erase)
        ws[WVO + b * 128 + t] = p[128 + t];               // write vector
        // out[b, w*4+r] = 1e-6 * read_modes[1][r]  (read_vectors collapse)
        float4 o = {1e-6f * rm1[0], 1e-6f * rm1[1], 1e-6f * rm1[2], 1e-6f * rm1[3]};
        ((float4*)(out + OUT_OFF))[b * 128 + t] = o;
    }

    if (t == 0) {
        const float inv1024 = 1.0f / 1024.0f;
        float ret = 1.f;
        #pragma unroll
        for (int r = 0; r < 4; ++r) {
            ws[RWV + b * 4 + r] = rm1[r] * inv1024;       // rw value per head
            float fg = sigmoidf_(p[256 + r]);
            ret *= (1.f - fg * rm1[r] * inv1024);
        }
        float u = 1e-6f * ret;                            // usage (constant over n)
        float ag = sigmoidf_(p[260]);
        float wg = sigmoidf_(p[261]);
        ws[SCAL + b * 2 + 0] = u;
        ws[SCAL + b * 2 + 1] = wg * (1.f - ag) * inv1024; // ww for n>=64 (alloc underflowed)
        float cum = 1.f;                                  // same f32 cumprod as reference
        for (int n = 0; n < 64; ++n) {
            float alloc = (1.f - u) * cum;
            ws[WWH + b * 64 + n] = wg * (ag * alloc + (1.f - ag) * inv1024);
            cum *= u;
        }
    }
}

// K3 (kW): all output writes. 9248 blocks x 256 threads x 4 plain float4 stores.
// Each block owns one contiguous 16 KB region (1024 float4 units). [R10-identical]
__global__ __launch_bounds__(256) void kW(const float* __restrict__ ws,
                                          float* __restrict__ out) {
    const int t = threadIdx.x;
    float4* out4 = (float4*)out;
    const float4 z4 = {0.f, 0.f, 0.f, 0.f};
    #pragma unroll
    for (int i = 0; i < 4; ++i) {
        int idx = blockIdx.x * 1024 + i * 256 + t;
        if (idx < L_END) {
            out4[LINK_OFF / 4 + idx] = z4;
        } else if (idx < M_END) {
            int j = idx - L_END;
            int w4 = j & 31;
            int n  = (j >> 5) & 1023;
            int b  = j >> 15;
            float ww = (n < 64) ? ws[WWH + b * 64 + n] : ws[SCAL + b * 2 + 1];
            float4 e = ((const float4*)(ws + EVO))[b * 32 + w4];
            float4 v = ((const float4*)(ws + WVO))[b * 32 + w4];
            float4 m;
            m.x = 1e-6f * (1.f - ww * e.x) + ww * v.x;
            m.y = 1e-6f * (1.f - ww * e.y) + ww * v.y;
            m.z = 1e-6f * (1.f - ww * e.z) + ww * v.z;
            m.w = 1e-6f * (1.f - ww * e.w) + ww * v.w;
            out4[MEM_OFF / 4 + j] = m;
        } else if (idx < U_END) {
            int j = idx - M_END;               // 0..8191; b = j>>8
            float u = ws[SCAL + (j >> 8) * 2 + 0];
            float4 uv = {u, u, u, u};
            out4[USAGE_OFF / 4 + j] = uv;
        } else if (idx < WW_END) {
            int j = (idx < P_END) ? idx - U_END : idx - P_END;
            int b = j >> 8, n0 = (j & 255) * 4;
            float wwc = ws[SCAL + b * 2 + 1];
            float4 wv;
            wv.x = (n0 + 0 < 64) ? ws[WWH + b * 64 + n0 + 0] : wwc;
            wv.y = (n0 + 1 < 64) ? ws[WWH + b * 64 + n0 + 1] : wwc;
            wv.z = (n0 + 2 < 64) ? ws[WWH + b * 64 + n0 + 2] : wwc;
            wv.w = (n0 + 3 < 64) ? ws[WWH + b * 64 + n0 + 3] : wwc;
            // prec = ww (prec0 = 0)
            out4[((idx < P_END) ? PREC_OFF : WW_OFF) / 4 + j] = wv;
        } else {
            int j = idx - WW_END;              // 0..32767; b = j>>10
            float4 rv = ((const float4*)(ws + RWV))[j >> 10];
            out4[RW_OFF / 4 + j] = rv;         // rw[b,n,:] constant over n
        }
    }
}

extern "C" void kernel_launch(void* const* d_in, const int* in_sizes, int n_in,
                              void* d_out, int out_size, void* d_ws, size_t ws_size,
                              hipStream_t stream) {
    const float* x   = (const float*)d_in[0];
    const float* Wif = (const float*)d_in[1];
    float* out = (float*)d_out;
    float* ws  = (float*)d_ws;

    k_reduce_x<<<dim3(64, 32), 128, 0, stream>>>(x, ws);
    kB<<<32, 512, 0, stream>>>(ws, Wif, out);
    kW<<<KW_BLOCKS, 256, 0, stream>>>(ws, out);
}